// Round 10
// baseline (211.380 us; speedup 1.0000x reference)
//
#include <hip/hip_runtime.h>
#include <hip/hip_bf16.h>
#include <hip/hip_fp16.h>

// GCN forward: emb-gather -> GCNConv(64->128) -> ReLU -> GCNConv(128->128) -> ReLU
//              -> global_max_pool -> Linear(128->10)
// N=100000, E=600000, VOCAB=5000, G=2000, C=10.
// Aggregations use packed-fp16 accumulation (1 v_pk_fma_f16 per edge-lane) with f32
// batch flushes; invalid batch slots read a zero row (e16[VOCAB] / P[N]).
// CSR via shift trick: fill bumps exc[] in place; rs[i+1] = exc[i]+bs[i>>8] afterwards.

typedef _Float16 h8 __attribute__((ext_vector_type(8)));
typedef float f32x4 __attribute__((ext_vector_type(4)));
struct H22 { __half2 a, b; };  // 8B: 4 fp16 features

// Zero deg, pool, and the two zero rows (e16[VOCAB], P[N]).
__global__ __launch_bounds__(256) void k_zero(int4* __restrict__ deg4, int n4i,
                                              int4* __restrict__ pool4, int p4i,
                                              int4* __restrict__ e16z, int4* __restrict__ Pz) {
    int t = blockIdx.x * 256 + threadIdx.x;
    int4 z = make_int4(0, 0, 0, 0);
    if (t < n4i) deg4[t] = z;
    if (t < p4i) pool4[t] = z;
    if (t < 8) e16z[t] = z;
    if (t < 16) Pz[t] = z;
}

// Fused: [0,gE) degree atomics; [gE,gE+nCast) e16 = fp16(emb); then W1T; then W2T.
__global__ __launch_bounds__(256) void k_degprep(const int* __restrict__ dst, int* __restrict__ deg, int E,
                                                 const float* __restrict__ emb, __half2* __restrict__ e16,
                                                 const float* __restrict__ W1, _Float16* __restrict__ W1T,
                                                 const float* __restrict__ W2, _Float16* __restrict__ W2T,
                                                 int nEmbF, int gE, int nCast) {
    int bid = blockIdx.x;
    if (bid < gE) {
        int e = bid * 256 + threadIdx.x;
        if (e < E) atomicAdd(&deg[dst[e]], 1);
    } else if (bid < gE + nCast) {
        int t = (bid - gE) * 256 + threadIdx.x;  // one thread = 4 floats
        if (t * 4 < nEmbF) {
            float4 v = *(const float4*)&emb[t * 4];
            e16[t * 2] = __floats2half2_rn(v.x, v.y);
            e16[t * 2 + 1] = __floats2half2_rn(v.z, v.w);
        }
    } else if (bid < gE + nCast + 32) {
        int t = (bid - gE - nCast) * 256 + threadIdx.x;  // 128*64
        int c = t >> 6, k = t & 63;
        W1T[c * 64 + k] = (_Float16)W1[k * 128 + c];
    } else {
        int t = (bid - gE - nCast - 32) * 256 + threadIdx.x;  // 128*128
        if (t < 128 * 128) {
            int c = t >> 7, k = t & 127;
            W2T[c * 128 + k] = (_Float16)W2[k * 128 + c];
        }
    }
}

// scan1 + dinv fused: exc = within-block exclusive scan of deg, bsums = block sums
__global__ __launch_bounds__(256) void k_scan1(const int* __restrict__ deg, int* __restrict__ exc,
                                               int* __restrict__ bsums, float* __restrict__ dinv, int N) {
    __shared__ int s[256];
    int i = blockIdx.x * 256 + threadIdx.x;
    int v = (i < N) ? deg[i] : 0;
    if (i < N) dinv[i] = rsqrtf((float)(v + 1));  // +1 self-loop
    s[threadIdx.x] = v;
    __syncthreads();
    for (int off = 1; off < 256; off <<= 1) {
        int t = (threadIdx.x >= (unsigned)off) ? s[threadIdx.x - off] : 0;
        __syncthreads();
        s[threadIdx.x] += t;
        __syncthreads();
    }
    if (i < N) exc[i] = s[threadIdx.x] - v;
    if (threadIdx.x == 255) bsums[blockIdx.x] = s[255];
}

// Exclusive scan of bsums in place (nb <= 512)
__global__ __launch_bounds__(512) void k_scan2(int* __restrict__ bsums, int nb) {
    __shared__ int s[512];
    int i = threadIdx.x;
    int v = (i < nb) ? bsums[i] : 0;
    s[i] = v;
    __syncthreads();
    for (int off = 1; off < 512; off <<= 1) {
        int t = (i >= off) ? s[i - off] : 0;
        __syncthreads();
        s[i] += t;
        __syncthreads();
    }
    if (i < nb) bsums[i] = s[i] - v;
}

// CSR fill, bumping exc in place. After this kernel: rs[i+1] == exc[i] + bs[i>>8].
// ed[pos] = {x[src], dinv[src] as splatted half2 bits}; cols[pos] = src.
__global__ __launch_bounds__(256) void k_fill(const int* __restrict__ src, const int* __restrict__ dst,
                                              const int* __restrict__ x, const float* __restrict__ dinv,
                                              int* __restrict__ exc, const int* __restrict__ bs,
                                              int* __restrict__ cols, int2* __restrict__ ed, int E) {
    int e = blockIdx.x * 256 + threadIdx.x;
    if (e < E) {
        int d = dst[e];
        int s = src[e];
        int pos = atomicAdd(&exc[d], 1) + bs[d >> 8];
        cols[pos] = s;
        unsigned int u = (unsigned int)__half_as_ushort(__float2half(dinv[s]));
        ed[pos] = make_int2(x[s], (int)(u | (u << 16)));
    }
}

// Fused node pipeline: 512 threads, block = 32 nodes.
// Phase 1: 16 half-waves x 2 nodes, single pass: Xs = di*(di*e16[x_i] + sum_j dj*e16[x_j]).
//          Per edge-lane: 1 v_pk_fma_f16 (weights pre-splatted fp16); f32 flush at end.
// Phase 2: Hs = relu(Xs @ W1 + b1)  (8 waves: 2 row-blocks x 4 col-quarters, MFMA)
// Phase 3: P  = dinv * (Hs @ W2)
__global__ __launch_bounds__(512) void k_mlp(const __half2* __restrict__ e16, const int* __restrict__ x,
                                             const float* __restrict__ dinv, const int* __restrict__ exc,
                                             const int* __restrict__ bs, const int2* __restrict__ ed,
                                             const _Float16* __restrict__ W1T, const float* __restrict__ b1,
                                             const _Float16* __restrict__ W2T, _Float16* __restrict__ P,
                                             int N, int VOCAB, int E) {
    __shared__ _Float16 Xs[32][72];
    __shared__ _Float16 Hs[32][136];
    int tid = threadIdx.x;
    int blk0 = blockIdx.x * 32;
    {
        int lane = tid & 31;
        int hw = tid >> 5;  // 0..15
        int nlA = hw * 2, nlB = hw * 2 + 1;
        int gA = blk0 + nlA; if (gA >= N) gA = N - 1;
        int gB = blk0 + nlB; if (gB >= N) gB = N - 1;
        int cA1 = exc[gA] + bs[gA >> 8];
        int cA0 = gA ? exc[gA - 1] + bs[(gA - 1) >> 8] : 0;
        int cB1 = exc[gB] + bs[gB >> 8];
        int cB0 = gB ? exc[gB - 1] + bs[(gB - 1) >> 8] : 0;
        float dA = dinv[gA], dB = dinv[gB];
        __half2 sA = e16[(size_t)x[gA] * 32 + lane];
        __half2 sB = e16[(size_t)x[gB] * 32 + lane];
        __half2 z2 = __float2half2_rn(0.f);
        __half2 aA0 = z2, aA1 = z2, aB0 = z2, aB1 = z2;
        int Emax = E - 1;
        // initial dual 8-deep batch
        {
            __half2 tA[8], tB[8], wA[8], wB[8];
#pragma unroll
            for (int i = 0; i < 8; ++i) {
                int ei = cA0 + i;
                int ec = min(ei, Emax);
                int2 r2 = ed[ec];
                int rx = (ei < cA1) ? r2.x : VOCAB;
                tA[i] = e16[(size_t)rx * 32 + lane];
                wA[i] = *reinterpret_cast<const __half2*>(&r2.y);
            }
#pragma unroll
            for (int i = 0; i < 8; ++i) {
                int ei = cB0 + i;
                int ec = min(ei, Emax);
                int2 r2 = ed[ec];
                int rx = (ei < cB1) ? r2.x : VOCAB;
                tB[i] = e16[(size_t)rx * 32 + lane];
                wB[i] = *reinterpret_cast<const __half2*>(&r2.y);
            }
#pragma unroll
            for (int i = 0; i < 8; i += 2) {
                aA0 = __hfma2(wA[i], tA[i], aA0);
                aA1 = __hfma2(wA[i + 1], tA[i + 1], aA1);
                aB0 = __hfma2(wB[i], tB[i], aB0);
                aB1 = __hfma2(wB[i + 1], tB[i + 1], aB1);
            }
        }
        // tails (8-deep)
        for (int e0 = cA0 + 8; e0 < cA1; e0 += 8) {
            __half2 t[8], w[8];
#pragma unroll
            for (int i = 0; i < 8; ++i) {
                int ei = e0 + i;
                int ec = min(ei, Emax);
                int2 r2 = ed[ec];
                int rx = (ei < cA1) ? r2.x : VOCAB;
                t[i] = e16[(size_t)rx * 32 + lane];
                w[i] = *reinterpret_cast<const __half2*>(&r2.y);
            }
#pragma unroll
            for (int i = 0; i < 8; i += 2) {
                aA0 = __hfma2(w[i], t[i], aA0);
                aA1 = __hfma2(w[i + 1], t[i + 1], aA1);
            }
        }
        for (int e0 = cB0 + 8; e0 < cB1; e0 += 8) {
            __half2 t[8], w[8];
#pragma unroll
            for (int i = 0; i < 8; ++i) {
                int ei = e0 + i;
                int ec = min(ei, Emax);
                int2 r2 = ed[ec];
                int rx = (ei < cB1) ? r2.x : VOCAB;
                t[i] = e16[(size_t)rx * 32 + lane];
                w[i] = *reinterpret_cast<const __half2*>(&r2.y);
            }
#pragma unroll
            for (int i = 0; i < 8; i += 2) {
                aB0 = __hfma2(w[i], t[i], aB0);
                aB1 = __hfma2(w[i + 1], t[i + 1], aB1);
            }
        }
        float2 mA0 = __half22float2(aA0), mA1 = __half22float2(aA1);
        float2 mB0 = __half22float2(aB0), mB1 = __half22float2(aB1);
        float mAx = mA0.x + mA1.x, mAy = mA0.y + mA1.y;
        float mBx = mB0.x + mB1.x, mBy = mB0.y + mB1.y;
        float2 fsA = __half22float2(sA), fsB = __half22float2(sB);
        *(__half2*)&Xs[nlA][lane * 2] =
            __floats2half2_rn(dA * fmaf(dA, fsA.x, mAx), dA * fmaf(dA, fsA.y, mAy));
        *(__half2*)&Xs[nlB][lane * 2] =
            __floats2half2_rn(dB * fmaf(dB, fsB.x, mBx), dB * fmaf(dB, fsB.y, mBy));
    }
    __syncthreads();
    int l = tid & 63, wid = tid >> 6;  // 8 waves
    int r = l & 15, kg = l >> 4;
    int rb = wid & 1;    // row block: 16 rows
    int cq = wid >> 1;   // col quarter: 32 cols
    // ---- Phase 2: Hs = relu(Xs @ W1 + b1), wave = 16 rows x 32 cols ----
    {
        f32x4 acc[2];
#pragma unroll
        for (int ct = 0; ct < 2; ++ct) acc[ct] = (f32x4){0.f, 0.f, 0.f, 0.f};
#pragma unroll
        for (int kc = 0; kc < 2; ++kc) {
            h8 a = *(const h8*)&Xs[rb * 16 + r][kc * 32 + kg * 8];
#pragma unroll
            for (int ct = 0; ct < 2; ++ct) {
                h8 b = *(const h8*)(W1T + (size_t)(cq * 32 + ct * 16 + r) * 64 + kc * 32 + kg * 8);
                acc[ct] = __builtin_amdgcn_mfma_f32_16x16x32_f16(a, b, acc[ct], 0, 0, 0);
            }
        }
#pragma unroll
        for (int ct = 0; ct < 2; ++ct) {
            float bias = b1[cq * 32 + ct * 16 + r];
#pragma unroll
            for (int i = 0; i < 4; ++i)
                Hs[rb * 16 + 4 * kg + i][cq * 32 + ct * 16 + r] =
                    (_Float16)fmaxf(acc[ct][i] + bias, 0.f);
        }
    }
    __syncthreads();
    // ---- Phase 3: P = dinv * (Hs @ W2), wave = 16 rows x 32 cols ----
    {
        f32x4 acc[2];
#pragma unroll
        for (int ct = 0; ct < 2; ++ct) acc[ct] = (f32x4){0.f, 0.f, 0.f, 0.f};
#pragma unroll
        for (int kc = 0; kc < 4; ++kc) {
            h8 a = *(const h8*)&Hs[rb * 16 + r][kc * 32 + kg * 8];
#pragma unroll
            for (int ct = 0; ct < 2; ++ct) {
                h8 b = *(const h8*)(W2T + (size_t)(cq * 32 + ct * 16 + r) * 128 + kc * 32 + kg * 8);
                acc[ct] = __builtin_amdgcn_mfma_f32_16x16x32_f16(a, b, acc[ct], 0, 0, 0);
            }
        }
        float dv[4];
#pragma unroll
        for (int i = 0; i < 4; ++i) {
            int gr = blk0 + rb * 16 + 4 * kg + i;
            dv[i] = (gr < N) ? dinv[gr] : 0.f;
        }
#pragma unroll
        for (int ct = 0; ct < 2; ++ct) {
#pragma unroll
            for (int i = 0; i < 4; ++i) {
                int gr = blk0 + rb * 16 + 4 * kg + i;
                if (gr < N)
                    P[(size_t)gr * 128 + cq * 32 + ct * 16 + r] = (_Float16)(acc[ct][i] * dv[i]);
            }
        }
    }
}

// Layer-2 + global_max_pool. 256-thr block = 8 half-waves x 2 nodes = 16 sorted nodes.
// 16-deep dual batches, per edge-lane: index-select + 2 v_pk_add_f16; f32 flush per batch.
// Invalid slots read zero row P[N]. LDS pool slots, one global emit per (block,graph,feat).
__global__ __launch_bounds__(256) void k_agg2pool(const H22* __restrict__ P22, const int* __restrict__ batch,
                                                  const float* __restrict__ dinv, const int* __restrict__ exc,
                                                  const int* __restrict__ bs, const int* __restrict__ cols,
                                                  const float4* __restrict__ bias4, float* __restrict__ pool,
                                                  int N, int E) {
    __shared__ int lpool[4][128];
    int tid = threadIdx.x;
    lpool[tid >> 7][tid & 127] = 0;
    lpool[(tid >> 7) + 2][tid & 127] = 0;
    __syncthreads();
    int lane = tid & 31;
    int blk_n0 = blockIdx.x * 16;
    int gfirst = batch[(blk_n0 < N) ? blk_n0 : (N - 1)];
    int n0 = blk_n0 + (tid >> 5) * 2;
    if (n0 < N) {
        int nA = n0;
        int nB = (n0 + 1 < N) ? n0 + 1 : n0;
        int cA1 = exc[nA] + bs[nA >> 8];
        int cA0 = nA ? exc[nA - 1] + bs[(nA - 1) >> 8] : 0;
        int cB1 = exc[nB] + bs[nB >> 8];
        int cB0 = nB ? exc[nB - 1] + bs[(nB - 1) >> 8] : 0;
        H22 sA = P22[(size_t)nA * 32 + lane];
        H22 sB = P22[(size_t)nB * 32 + lane];
        float2 fa = __half22float2(sA.a), fb = __half22float2(sA.b);
        float aA[4] = {fa.x, fa.y, fb.x, fb.y};
        fa = __half22float2(sB.a); fb = __half22float2(sB.b);
        float aB[4] = {fa.x, fa.y, fb.x, fb.y};
        int Emax = E - 1;
        __half2 z2 = __float2half2_rn(0.f);
        // initial dual 16-deep batch
        {
            H22 tA[16], tB[16];
#pragma unroll
            for (int i = 0; i < 16; ++i) {
                int ei = cA0 + i;
                int ec = min(ei, Emax);
                int col = (ei < cA1) ? cols[ec] : N;
                tA[i] = P22[(size_t)col * 32 + lane];
            }
#pragma unroll
            for (int i = 0; i < 16; ++i) {
                int ei = cB0 + i;
                int ec = min(ei, Emax);
                int col = (ei < cB1) ? cols[ec] : N;
                tB[i] = P22[(size_t)col * 32 + lane];
            }
            __half2 pA0 = z2, pA1 = z2, pA2 = z2, pA3 = z2;
            __half2 pB0 = z2, pB1 = z2, pB2 = z2, pB3 = z2;
#pragma unroll
            for (int i = 0; i < 16; i += 2) {
                pA0 = __hadd2(pA0, tA[i].a);
                pA1 = __hadd2(pA1, tA[i].b);
                pA2 = __hadd2(pA2, tA[i + 1].a);
                pA3 = __hadd2(pA3, tA[i + 1].b);
                pB0 = __hadd2(pB0, tB[i].a);
                pB1 = __hadd2(pB1, tB[i].b);
                pB2 = __hadd2(pB2, tB[i + 1].a);
                pB3 = __hadd2(pB3, tB[i + 1].b);
            }
            float2 q0 = __half22float2(pA0), q1 = __half22float2(pA2);
            float2 q2 = __half22float2(pA1), q3 = __half22float2(pA3);
            aA[0] += q0.x + q1.x; aA[1] += q0.y + q1.y;
            aA[2] += q2.x + q3.x; aA[3] += q2.y + q3.y;
            q0 = __half22float2(pB0); q1 = __half22float2(pB2);
            q2 = __half22float2(pB1); q3 = __half22float2(pB3);
            aB[0] += q0.x + q1.x; aB[1] += q0.y + q1.y;
            aB[2] += q2.x + q3.x; aB[3] += q2.y + q3.y;
        }
        // tails (8-deep), rare (deg > 16)
        for (int e0 = cA0 + 16; e0 < cA1; e0 += 8) {
            H22 t[8];
#pragma unroll
            for (int i = 0; i < 8; ++i) {
                int ei = e0 + i;
                int ec = min(ei, Emax);
                int col = (ei < cA1) ? cols[ec] : N;
                t[i] = P22[(size_t)col * 32 + lane];
            }
            __half2 p0 = z2, p1 = z2;
#pragma unroll
            for (int i = 0; i < 8; ++i) {
                p0 = __hadd2(p0, t[i].a);
                p1 = __hadd2(p1, t[i].b);
            }
            float2 q0 = __half22float2(p0), q1 = __half22float2(p1);
            aA[0] += q0.x; aA[1] += q0.y; aA[2] += q1.x; aA[3] += q1.y;
        }
        for (int e0 = cB0 + 16; e0 < cB1; e0 += 8) {
            H22 t[8];
#pragma unroll
            for (int i = 0; i < 8; ++i) {
                int ei = e0 + i;
                int ec = min(ei, Emax);
                int col = (ei < cB1) ? cols[ec] : N;
                t[i] = P22[(size_t)col * 32 + lane];
            }
            __half2 p0 = z2, p1 = z2;
#pragma unroll
            for (int i = 0; i < 8; ++i) {
                p0 = __hadd2(p0, t[i].a);
                p1 = __hadd2(p1, t[i].b);
            }
            float2 q0 = __half22float2(p0), q1 = __half22float2(p1);
            aB[0] += q0.x; aB[1] += q0.y; aB[2] += q1.x; aB[3] += q1.y;
        }
        float dA = dinv[nA], dB = dinv[nB];
        int gA = batch[nA], gB = batch[nB];
        float4 b = bias4[lane];
        float bv[4] = {b.x, b.y, b.z, b.w};
        float zA[4], zB[4];
#pragma unroll
        for (int f = 0; f < 4; ++f) {
            zA[f] = fmaxf(fmaf(dA, aA[f], bv[f]), 0.f);
            zB[f] = fmaxf(fmaf(dB, aB[f], bv[f]), 0.f);
        }
        int rot = (lane >> 3) & 3;  // bank-rotation for LDS atomics
        auto emit = [&](int g, const float* m) {
            int slot = g - gfirst;
            if (slot < 4) {
#pragma unroll
                for (int f = 0; f < 4; ++f) {
                    int ff = (f + rot) & 3;
                    if (m[ff] > 0.f) atomicMax(&lpool[slot][lane * 4 + ff], __float_as_int(m[ff]));
                }
            } else {
                float* pg = pool + (size_t)g * 128 + lane * 4;
#pragma unroll
                for (int f = 0; f < 4; ++f)
                    if (m[f] > 0.f) atomicMax((int*)(pg + f), __float_as_int(m[f]));
            }
        };
        if (gA == gB) {
            float m[4];
#pragma unroll
            for (int f = 0; f < 4; ++f) m[f] = fmaxf(zA[f], zB[f]);
            emit(gA, m);
        } else {
            emit(gA, zA);
            emit(gB, zB);
        }
    }
    __syncthreads();
    {
        int f = tid & 127;
        for (int s = tid >> 7; s < 4; s += 2) {
            int v = lpool[s][f];
            if (v > 0) atomicMax((int*)&pool[(size_t)(gfirst + s) * 128 + f], v);
        }
    }
}

// out[g][c] = blin[c] + sum_f pool[g][f] * Wlin[f][c]
__global__ __launch_bounds__(256) void k_final(const float* __restrict__ pool, const float* __restrict__ Wlin,
                                               const float* __restrict__ blin, float* __restrict__ out, int G) {
    int t = blockIdx.x * 256 + threadIdx.x;
    if (t >= G * 10) return;
    int g = t / 10, c = t % 10;
    float acc = blin[c];
    const float* pr = pool + (size_t)g * 128;
#pragma unroll 8
    for (int f = 0; f < 128; ++f) acc = fmaf(pr[f], Wlin[f * 10 + c], acc);
    out[t] = acc;
}

extern "C" void kernel_launch(void* const* d_in, const int* in_sizes, int n_in,
                              void* d_out, int out_size, void* d_ws, size_t ws_size,
                              hipStream_t stream) {
    const int* x = (const int*)d_in[0];
    const int* ei = (const int*)d_in[1];
    const int* batch = (const int*)d_in[2];
    const float* emb = (const float*)d_in[4];
    const float* W1 = (const float*)d_in[5];
    const float* b1 = (const float*)d_in[6];
    const float* W2 = (const float*)d_in[7];
    const float* b2 = (const float*)d_in[8];
    const float* Wlin = (const float*)d_in[9];
    const float* blin = (const float*)d_in[10];
    float* out = (float*)d_out;

    int N = in_sizes[0];
    int E = in_sizes[1] / 2;
    int VOCAB = in_sizes[4] / 64;
    int G = out_size / 10;
    const int* srcp = ei;
    const int* dstp = ei + E;

    char* p = (char*)d_ws;
    auto alloc = [&](size_t bytes) -> char* {
        char* r = p;
        p += (bytes + 255) & ~(size_t)255;
        return r;
    };
    int* deg = (int*)alloc((size_t)N * 4);
    int* exc = (int*)alloc((size_t)N * 4);
    int* bsums = (int*)alloc(512 * 4);
    float* dinv = (float*)alloc((size_t)N * 4);
    int2* ed = (int2*)alloc((size_t)E * 8);
    int* cols = (int*)alloc((size_t)E * 4);
    _Float16* e16 = (_Float16*)alloc((size_t)(VOCAB + 1) * 64 * 2);  // +1 zero row
    _Float16* W1T = (_Float16*)alloc(128 * 64 * 2);
    _Float16* W2T = (_Float16*)alloc(128 * 128 * 2);
    _Float16* P = (_Float16*)alloc((size_t)(N + 1) * 128 * 2);       // +1 zero row
    float* pool = (float*)alloc((size_t)G * 128 * 4);

    int gE = (E + 255) / 256;
    int gN = (N + 255) / 256;  // 391 <= 512 (scan2 capacity)
    int nEmbF = VOCAB * 64;
    int nCast = (nEmbF / 4 + 255) / 256;

    int n4i = N / 4, p4i = G * 128 / 4;
    int zg = ((n4i > p4i ? n4i : p4i) + 255) / 256;
    k_zero<<<zg, 256, 0, stream>>>((int4*)deg, n4i, (int4*)pool, p4i,
                                   (int4*)(e16 + (size_t)VOCAB * 64), (int4*)(P + (size_t)N * 128));
    k_degprep<<<gE + nCast + 32 + 64, 256, 0, stream>>>(dstp, deg, E, emb, (__half2*)e16, W1, W1T,
                                                        W2, W2T, nEmbF, gE, nCast);
    k_scan1<<<gN, 256, 0, stream>>>(deg, exc, bsums, dinv, N);
    k_scan2<<<1, 512, 0, stream>>>(bsums, gN);
    k_fill<<<gE, 256, 0, stream>>>(srcp, dstp, x, dinv, exc, bsums, cols, ed, E);
    k_mlp<<<(N + 31) / 32, 512, 0, stream>>>((const __half2*)e16, x, dinv, exc, bsums, ed, W1T, b1,
                                             W2T, P, N, VOCAB, E);
    k_agg2pool<<<(N + 15) / 16, 256, 0, stream>>>((const H22*)P, batch, dinv, exc, bsums, cols,
                                                  (const float4*)b2, pool, N, E);
    k_final<<<(G * 10 + 255) / 256, 256, 0, stream>>>(pool, Wlin, blin, out, G);
}

// Round 11
// 197.601 us; speedup vs baseline: 1.0697x; 1.0697x over previous
//
#include <hip/hip_runtime.h>
#include <hip/hip_bf16.h>
#include <hip/hip_fp16.h>

// GCN forward: emb-gather -> GCNConv(64->128) -> ReLU -> GCNConv(128->128) -> ReLU
//              -> global_max_pool -> Linear(128->10)
// N=100000, E=600000, VOCAB=5000, G=2000, C=10.
// Layer-1 aggregation in 64-dim embedding space (exact by linearity): k_agge (barrier-free
// gather) -> Xagg fp16 -> k_gemm12 (MFMA gemm1 -> LDS -> MFMA gemm2) -> P fp16.
// Edge record: one int4 {x[src], dinv[src] bits, src, 0} -> single scattered store in fill.

typedef _Float16 h8 __attribute__((ext_vector_type(8)));
typedef _Float16 h4v __attribute__((ext_vector_type(4)));
typedef float f32x4 __attribute__((ext_vector_type(4)));

// Zero deg, pool, and the Xagg pad rows.
__global__ __launch_bounds__(256) void k_zero(int4* __restrict__ deg4, int n4i,
                                              int4* __restrict__ pool4, int p4i,
                                              int4* __restrict__ xpad, int x4i) {
    int t = blockIdx.x * 256 + threadIdx.x;
    int4 z = make_int4(0, 0, 0, 0);
    if (t < n4i) deg4[t] = z;
    if (t < p4i) pool4[t] = z;
    if (t < x4i) xpad[t] = z;
}

// Fused: [0,gE) degree atomics; [gE,gE+nCast) e16 = fp16(emb); then W1T; then W2T.
__global__ __launch_bounds__(256) void k_degprep(const int* __restrict__ dst, int* __restrict__ deg, int E,
                                                 const float* __restrict__ emb, __half2* __restrict__ e16,
                                                 const float* __restrict__ W1, _Float16* __restrict__ W1T,
                                                 const float* __restrict__ W2, _Float16* __restrict__ W2T,
                                                 int nEmbF, int gE, int nCast) {
    int bid = blockIdx.x;
    if (bid < gE) {
        int e = bid * 256 + threadIdx.x;
        if (e < E) atomicAdd(&deg[dst[e]], 1);
    } else if (bid < gE + nCast) {
        int t = (bid - gE) * 256 + threadIdx.x;  // one thread = 4 floats
        if (t * 4 < nEmbF) {
            float4 v = *(const float4*)&emb[t * 4];
            e16[t * 2] = __floats2half2_rn(v.x, v.y);
            e16[t * 2 + 1] = __floats2half2_rn(v.z, v.w);
        }
    } else if (bid < gE + nCast + 32) {
        int t = (bid - gE - nCast) * 256 + threadIdx.x;  // 128*64
        int c = t >> 6, k = t & 63;
        W1T[c * 64 + k] = (_Float16)W1[k * 128 + c];
    } else {
        int t = (bid - gE - nCast - 32) * 256 + threadIdx.x;  // 128*128
        if (t < 128 * 128) {
            int c = t >> 7, k = t & 127;
            W2T[c * 128 + k] = (_Float16)W2[k * 128 + c];
        }
    }
}

// scan1 + dinv fused
__global__ __launch_bounds__(256) void k_scan1(const int* __restrict__ deg, int* __restrict__ exc,
                                               int* __restrict__ bsums, float* __restrict__ dinv, int N) {
    __shared__ int s[256];
    int i = blockIdx.x * 256 + threadIdx.x;
    int v = (i < N) ? deg[i] : 0;
    if (i < N) dinv[i] = rsqrtf((float)(v + 1));  // +1 self-loop
    s[threadIdx.x] = v;
    __syncthreads();
    for (int off = 1; off < 256; off <<= 1) {
        int t = (threadIdx.x >= (unsigned)off) ? s[threadIdx.x - off] : 0;
        __syncthreads();
        s[threadIdx.x] += t;
        __syncthreads();
    }
    if (i < N) exc[i] = s[threadIdx.x] - v;
    if (threadIdx.x == 255) bsums[blockIdx.x] = s[255];
}

__global__ __launch_bounds__(512) void k_scan2(int* __restrict__ bsums, int nb) {
    __shared__ int s[512];
    int i = threadIdx.x;
    int v = (i < nb) ? bsums[i] : 0;
    s[i] = v;
    __syncthreads();
    for (int off = 1; off < 512; off <<= 1) {
        int t = (i >= off) ? s[i - off] : 0;
        __syncthreads();
        s[i] += t;
        __syncthreads();
    }
    if (i < nb) bsums[i] = s[i] - v;
}

__global__ __launch_bounds__(256) void k_scan3(int* __restrict__ rowstart, int* __restrict__ cursor,
                                               const int* __restrict__ bsums, int N, int E) {
    int i = blockIdx.x * 256 + threadIdx.x;
    if (i < N) {
        int r = rowstart[i] + bsums[blockIdx.x];
        rowstart[i] = r;
        cursor[i] = r;
    }
    if (i == 0 && blockIdx.x == 0) rowstart[N] = E;
}

// CSR fill: rec[pos] = {x[src], dinv[src] bits, src, 0} — ONE 16B scattered store.
__global__ __launch_bounds__(256) void k_fill(const int* __restrict__ src, const int* __restrict__ dst,
                                              const int* __restrict__ x, const float* __restrict__ dinv,
                                              int* __restrict__ cursor, int4* __restrict__ rec, int E) {
    int e = blockIdx.x * 256 + threadIdx.x;
    if (e < E) {
        int d = dst[e];
        int s = src[e];
        int pos = atomicAdd(&cursor[d], 1);
        rec[pos] = make_int4(x[s], __float_as_int(dinv[s]), s, 0);
    }
}

// 64-dim embedding-space aggregation (barrier-free): Xagg[i] = di*(di*e16[x_i] + sum dj*e16[x_j]).
// 256 thr = 8 half-waves x 2 nodes; dual 8-deep clamped gather batches.
__global__ __launch_bounds__(256) void k_agge(const __half2* __restrict__ e16, const int* __restrict__ x,
                                              const float* __restrict__ dinv, const int* __restrict__ rs,
                                              const int4* __restrict__ rec, __half2* __restrict__ Xagg, int N) {
    int lane = threadIdx.x & 31;
    int n0 = (blockIdx.x * 8 + (threadIdx.x >> 5)) * 2;
    if (n0 >= N) return;
    int nB = (n0 + 1 < N) ? n0 + 1 : n0;
    int cA0 = rs[n0], cA1 = rs[n0 + 1];
    int cB0 = rs[nB], cB1 = rs[nB + 1];
    bool hasA = cA0 < cA1, hasB = cB0 < cB1;
    __half2 tA[8], tB[8];
    float wA[8], wB[8];
#pragma unroll
    for (int i = 0; i < 8; ++i) {
        int ei = cA0 + i;
        int ec = (ei < cA1) ? ei : (hasA ? cA1 - 1 : 0);
        int4 r2 = rec[ec];
        tA[i] = e16[(size_t)r2.x * 32 + lane];
        wA[i] = (ei < cA1) ? __int_as_float(r2.y) : 0.f;
    }
#pragma unroll
    for (int i = 0; i < 8; ++i) {
        int ei = cB0 + i;
        int ec = (ei < cB1) ? ei : (hasB ? cB1 - 1 : 0);
        int4 r2 = rec[ec];
        tB[i] = e16[(size_t)r2.x * 32 + lane];
        wB[i] = (ei < cB1) ? __int_as_float(r2.y) : 0.f;
    }
    float dA = dinv[n0], dB = dinv[nB];
    float2 sA = __half22float2(e16[(size_t)x[n0] * 32 + lane]);
    float2 sB = __half22float2(e16[(size_t)x[nB] * 32 + lane]);
    float aA0 = dA * sA.x, aA1 = dA * sA.y;
    float aB0 = dB * sB.x, aB1 = dB * sB.y;
#pragma unroll
    for (int i = 0; i < 8; ++i) {
        float2 tf = __half22float2(tA[i]);
        aA0 = fmaf(wA[i], tf.x, aA0);
        aA1 = fmaf(wA[i], tf.y, aA1);
    }
#pragma unroll
    for (int i = 0; i < 8; ++i) {
        float2 tf = __half22float2(tB[i]);
        aB0 = fmaf(wB[i], tf.x, aB0);
        aB1 = fmaf(wB[i], tf.y, aB1);
    }
    for (int e = cA0 + 8; e < cA1; e += 8) {
#pragma unroll
        for (int i = 0; i < 8; ++i) {
            int ei = e + i;
            int ec = (ei < cA1) ? ei : cA1 - 1;
            int4 r2 = rec[ec];
            tA[i] = e16[(size_t)r2.x * 32 + lane];
            wA[i] = (ei < cA1) ? __int_as_float(r2.y) : 0.f;
        }
#pragma unroll
        for (int i = 0; i < 8; ++i) {
            float2 tf = __half22float2(tA[i]);
            aA0 = fmaf(wA[i], tf.x, aA0);
            aA1 = fmaf(wA[i], tf.y, aA1);
        }
    }
    for (int e = cB0 + 8; e < cB1; e += 8) {
#pragma unroll
        for (int i = 0; i < 8; ++i) {
            int ei = e + i;
            int ec = (ei < cB1) ? ei : cB1 - 1;
            int4 r2 = rec[ec];
            tB[i] = e16[(size_t)r2.x * 32 + lane];
            wB[i] = (ei < cB1) ? __int_as_float(r2.y) : 0.f;
        }
#pragma unroll
        for (int i = 0; i < 8; ++i) {
            float2 tf = __half22float2(tB[i]);
            aB0 = fmaf(wB[i], tf.x, aB0);
            aB1 = fmaf(wB[i], tf.y, aB1);
        }
    }
    Xagg[(size_t)n0 * 32 + lane] = __floats2half2_rn(dA * aA0, dA * aA1);
    Xagg[(size_t)nB * 32 + lane] = __floats2half2_rn(dB * aB0, dB * aB1);
}

// Fused double GEMM: Hs = relu(Xagg @ W1 + b1) -> LDS -> P = dinv * (Hs @ W2).
// 256 thr = 4 waves x 16 rows; block = 64 rows. Xagg padded to 64-multiple (pad zeroed).
__global__ __launch_bounds__(256) void k_gemm12(const _Float16* __restrict__ Xagg,
                                                const _Float16* __restrict__ W1T, const float* __restrict__ b1,
                                                const _Float16* __restrict__ W2T, const float* __restrict__ dinv,
                                                _Float16* __restrict__ P, int N) {
    __shared__ _Float16 Hs[64][136];
    int tid = threadIdx.x;
    int l = tid & 63, wid = tid >> 6;  // 4 waves
    int r = l & 15, kg = l >> 4;
    int blk0 = blockIdx.x * 64;
    // gemm1: wave = 16 rows x 128 cols
    {
        f32x4 acc[8];
#pragma unroll
        for (int ct = 0; ct < 8; ++ct) acc[ct] = (f32x4){0.f, 0.f, 0.f, 0.f};
        const _Float16* ab = Xagg + (size_t)(blk0 + wid * 16 + r) * 64 + kg * 8;
#pragma unroll
        for (int kc = 0; kc < 2; ++kc) {
            h8 a = *(const h8*)(ab + kc * 32);
#pragma unroll
            for (int ct = 0; ct < 8; ++ct) {
                h8 b = *(const h8*)(W1T + (size_t)(ct * 16 + r) * 64 + kc * 32 + kg * 8);
                acc[ct] = __builtin_amdgcn_mfma_f32_16x16x32_f16(a, b, acc[ct], 0, 0, 0);
            }
        }
#pragma unroll
        for (int ct = 0; ct < 8; ++ct) {
            float bias = b1[ct * 16 + r];
#pragma unroll
            for (int i = 0; i < 4; ++i)
                Hs[wid * 16 + 4 * kg + i][ct * 16 + r] = (_Float16)fmaxf(acc[ct][i] + bias, 0.f);
        }
    }
    __syncthreads();
    // gemm2: wave = 16 rows x 128 cols
    {
        f32x4 acc[8];
#pragma unroll
        for (int ct = 0; ct < 8; ++ct) acc[ct] = (f32x4){0.f, 0.f, 0.f, 0.f};
#pragma unroll
        for (int kc = 0; kc < 4; ++kc) {
            h8 a = *(const h8*)&Hs[wid * 16 + r][kc * 32 + kg * 8];
#pragma unroll
            for (int ct = 0; ct < 8; ++ct) {
                h8 b = *(const h8*)(W2T + (size_t)(ct * 16 + r) * 128 + kc * 32 + kg * 8);
                acc[ct] = __builtin_amdgcn_mfma_f32_16x16x32_f16(a, b, acc[ct], 0, 0, 0);
            }
        }
        float dv[4];
#pragma unroll
        for (int i = 0; i < 4; ++i) {
            int gr = blk0 + wid * 16 + 4 * kg + i;
            dv[i] = (gr < N) ? dinv[gr] : 0.f;
        }
#pragma unroll
        for (int ct = 0; ct < 8; ++ct) {
#pragma unroll
            for (int i = 0; i < 4; ++i) {
                int gr = blk0 + wid * 16 + 4 * kg + i;
                if (gr < N) P[(size_t)gr * 128 + ct * 16 + r] = (_Float16)(acc[ct][i] * dv[i]);
            }
        }
    }
}

// Layer-2 + global_max_pool. 256-thr block = 8 half-waves x 2 nodes = 16 sorted nodes.
// 16-deep dual clamped gathers (weight-masked). LDS pool slots, one global emit per
// (block, graph, feature).
__global__ __launch_bounds__(256) void k_agg2pool(const h4v* __restrict__ P4, const int* __restrict__ batch,
                                                  const float* __restrict__ dinv, const int* __restrict__ rs,
                                                  const int4* __restrict__ rec, const float4* __restrict__ bias4,
                                                  float* __restrict__ pool, int N, int G) {
    __shared__ int lpool[4][128];
    int tid = threadIdx.x;
    lpool[tid >> 7][tid & 127] = 0;
    lpool[(tid >> 7) + 2][tid & 127] = 0;
    __syncthreads();
    int lane = tid & 31;
    int blk_n0 = blockIdx.x * 16;
    int gfirst = batch[(blk_n0 < N) ? blk_n0 : (N - 1)];
    int n0 = blk_n0 + (tid >> 5) * 2;
    if (n0 < N) {
        int nA = n0;
        int nB = (n0 + 1 < N) ? n0 + 1 : n0;
        int cA0 = rs[nA], cA1 = rs[nA + 1];
        int cB0 = rs[nB], cB1 = rs[nB + 1];
        bool hasA = cA0 < cA1, hasB = cB0 < cB1;
        h4v sA = P4[(size_t)nA * 32 + lane];
        h4v sB = P4[(size_t)nB * 32 + lane];
        float aA[4], aB[4];
#pragma unroll
        for (int f = 0; f < 4; ++f) {
            aA[f] = (float)sA[f];
            aB[f] = (float)sB[f];
        }
        {
            h4v tA[16], tB[16];
#pragma unroll
            for (int i = 0; i < 16; ++i) {
                int ei = cA0 + i;
                int ec = (ei < cA1) ? ei : (hasA ? cA1 - 1 : 0);
                tA[i] = P4[(size_t)rec[ec].z * 32 + lane];
            }
#pragma unroll
            for (int i = 0; i < 16; ++i) {
                int ei = cB0 + i;
                int ec = (ei < cB1) ? ei : (hasB ? cB1 - 1 : 0);
                tB[i] = P4[(size_t)rec[ec].z * 32 + lane];
            }
#pragma unroll
            for (int i = 0; i < 16; ++i) {
                float w = (cA0 + i < cA1) ? 1.f : 0.f;
#pragma unroll
                for (int f = 0; f < 4; ++f) aA[f] = fmaf(w, (float)tA[i][f], aA[f]);
            }
#pragma unroll
            for (int i = 0; i < 16; ++i) {
                float w = (cB0 + i < cB1) ? 1.f : 0.f;
#pragma unroll
                for (int f = 0; f < 4; ++f) aB[f] = fmaf(w, (float)tB[i][f], aB[f]);
            }
        }
        for (int e = cA0 + 16; e < cA1; e += 16) {
            h4v t[16];
#pragma unroll
            for (int i = 0; i < 16; ++i) {
                int ei = e + i;
                int ec = (ei < cA1) ? ei : cA1 - 1;
                t[i] = P4[(size_t)rec[ec].z * 32 + lane];
            }
#pragma unroll
            for (int i = 0; i < 16; ++i) {
                float w = (e + i < cA1) ? 1.f : 0.f;
#pragma unroll
                for (int f = 0; f < 4; ++f) aA[f] = fmaf(w, (float)t[i][f], aA[f]);
            }
        }
        for (int e = cB0 + 16; e < cB1; e += 16) {
            h4v t[16];
#pragma unroll
            for (int i = 0; i < 16; ++i) {
                int ei = e + i;
                int ec = (ei < cB1) ? ei : cB1 - 1;
                t[i] = P4[(size_t)rec[ec].z * 32 + lane];
            }
#pragma unroll
            for (int i = 0; i < 16; ++i) {
                float w = (e + i < cB1) ? 1.f : 0.f;
#pragma unroll
                for (int f = 0; f < 4; ++f) aB[f] = fmaf(w, (float)t[i][f], aB[f]);
            }
        }
        float dA = dinv[nA], dB = dinv[nB];
        int gA = batch[nA], gB = batch[nB];
        float4 b = bias4[lane];
        float bv[4] = {b.x, b.y, b.z, b.w};
        float zA[4], zB[4];
#pragma unroll
        for (int f = 0; f < 4; ++f) {
            zA[f] = fmaxf(fmaf(dA, aA[f], bv[f]), 0.f);
            zB[f] = fmaxf(fmaf(dB, aB[f], bv[f]), 0.f);
        }
        int rot = (lane >> 3) & 3;  // bank-rotation for LDS atomics
        auto emit = [&](int g, const float* m) {
            int slot = g - gfirst;
            if (slot < 4) {
#pragma unroll
                for (int f = 0; f < 4; ++f) {
                    int ff = (f + rot) & 3;
                    if (m[ff] > 0.f) atomicMax(&lpool[slot][lane * 4 + ff], __float_as_int(m[ff]));
                }
            } else {
                float* pg = pool + (size_t)g * 128 + lane * 4;
#pragma unroll
                for (int f = 0; f < 4; ++f)
                    if (m[f] > 0.f) atomicMax((int*)(pg + f), __float_as_int(m[f]));
            }
        };
        if (gA == gB) {
            float m[4];
#pragma unroll
            for (int f = 0; f < 4; ++f) m[f] = fmaxf(zA[f], zB[f]);
            emit(gA, m);
        } else {
            emit(gA, zA);
            emit(gB, zB);
        }
    }
    __syncthreads();
    {
        int f = tid & 127;
        for (int s = tid >> 7; s < 4; s += 2) {
            int v = lpool[s][f];
            if (v > 0) atomicMax((int*)&pool[(size_t)(gfirst + s) * 128 + f], v);
        }
    }
}

// out[g][c] = blin[c] + sum_f pool[g][f] * Wlin[f][c]
__global__ __launch_bounds__(256) void k_final(const float* __restrict__ pool, const float* __restrict__ Wlin,
                                               const float* __restrict__ blin, float* __restrict__ out, int G) {
    int t = blockIdx.x * 256 + threadIdx.x;
    if (t >= G * 10) return;
    int g = t / 10, c = t % 10;
    float acc = blin[c];
    const float* pr = pool + (size_t)g * 128;
#pragma unroll 8
    for (int f = 0; f < 128; ++f) acc = fmaf(pr[f], Wlin[f * 10 + c], acc);
    out[t] = acc;
}

extern "C" void kernel_launch(void* const* d_in, const int* in_sizes, int n_in,
                              void* d_out, int out_size, void* d_ws, size_t ws_size,
                              hipStream_t stream) {
    const int* x = (const int*)d_in[0];
    const int* ei = (const int*)d_in[1];
    const int* batch = (const int*)d_in[2];
    const float* emb = (const float*)d_in[4];
    const float* W1 = (const float*)d_in[5];
    const float* b1 = (const float*)d_in[6];
    const float* W2 = (const float*)d_in[7];
    const float* b2 = (const float*)d_in[8];
    const float* Wlin = (const float*)d_in[9];
    const float* blin = (const float*)d_in[10];
    float* out = (float*)d_out;

    int N = in_sizes[0];
    int E = in_sizes[1] / 2;
    int VOCAB = in_sizes[4] / 64;
    int G = out_size / 10;
    const int* srcp = ei;
    const int* dstp = ei + E;

    char* p = (char*)d_ws;
    auto alloc = [&](size_t bytes) -> char* {
        char* r = p;
        p += (bytes + 255) & ~(size_t)255;
        return r;
    };
    int Npad = (N + 63) & ~63;
    int* deg = (int*)alloc((size_t)N * 4);
    int* cursor = (int*)alloc((size_t)N * 4);
    int* rowstart = (int*)alloc((size_t)(N + 1) * 4);
    int* bsums = (int*)alloc(512 * 4);
    float* dinv = (float*)alloc((size_t)N * 4);
    int4* rec = (int4*)alloc((size_t)E * 16);
    _Float16* e16 = (_Float16*)alloc((size_t)VOCAB * 64 * 2);
    _Float16* W1T = (_Float16*)alloc(128 * 64 * 2);
    _Float16* W2T = (_Float16*)alloc(128 * 128 * 2);
    _Float16* Xagg = (_Float16*)alloc((size_t)Npad * 64 * 2);
    _Float16* P = (_Float16*)alloc((size_t)N * 128 * 2);
    float* pool = (float*)alloc((size_t)G * 128 * 4);

    int gE = (E + 255) / 256;
    int gN = (N + 255) / 256;  // 391 <= 512 (scan2 capacity)
    int nEmbF = VOCAB * 64;
    int nCast = (nEmbF / 4 + 255) / 256;

    int n4i = N / 4, p4i = G * 128 / 4;
    int x4i = (Npad - N) * 64 * 2 / 16;  // Xagg pad rows in int4s
    int zmax = n4i > p4i ? n4i : p4i;
    k_zero<<<(zmax + 255) / 256, 256, 0, stream>>>((int4*)deg, n4i, (int4*)pool, p4i,
                                                   (int4*)(Xagg + (size_t)N * 64), x4i);
    k_degprep<<<gE + nCast + 32 + 64, 256, 0, stream>>>(dstp, deg, E, emb, (__half2*)e16, W1, W1T,
                                                        W2, W2T, nEmbF, gE, nCast);
    k_scan1<<<gN, 256, 0, stream>>>(deg, rowstart, bsums, dinv, N);
    k_scan2<<<1, 512, 0, stream>>>(bsums, gN);
    k_scan3<<<gN, 256, 0, stream>>>(rowstart, cursor, bsums, N, E);
    k_fill<<<gE, 256, 0, stream>>>(srcp, dstp, x, dinv, cursor, rec, E);
    k_agge<<<(N + 15) / 16, 256, 0, stream>>>((const __half2*)e16, x, dinv, rowstart, rec,
                                              (__half2*)Xagg, N);
    k_gemm12<<<(N + 63) / 64, 256, 0, stream>>>(Xagg, W1T, b1, W2T, dinv, P, N);
    k_agg2pool<<<(N + 15) / 16, 256, 0, stream>>>((const h4v*)P, batch, dinv, rowstart, rec,
                                                  (const float4*)b2, pool, N, G);
    k_final<<<(G * 10 + 255) / 256, 256, 0, stream>>>(pool, Wlin, blin, out, G);
}